// Round 1
// baseline (17505.824 us; speedup 1.0000x reference)
//
#include <hip/hip_runtime.h>
#include <math.h>

// ---------------------------------------------------------------------------
// Faster R-CNN forward on MI355X — round 0: correctness-first fp32 pipeline.
// Workspace layout (floats), total ~90.6M floats = ~363 MB of d_ws.
// ---------------------------------------------------------------------------

#define NPOS 2294      // 37*62 RPN positions
#define FH 37
#define FW 62
#define NANCH 20646    // NPOS*9
#define NSORT 32768
#define PRE_NMS 6000
#define POST_NMS 300
#define NWORD 94       // ceil(6000/64)

__device__ const float ANCHORS[9][4] = {
    {-84.f,  -40.f,   99.f,  55.f},
    {-176.f, -88.f,  191.f, 103.f},
    {-360.f, -184.f, 375.f, 199.f},
    {-56.f,  -56.f,   71.f,  71.f},
    {-120.f, -120.f, 135.f, 135.f},
    {-248.f, -248.f, 263.f, 263.f},
    {-36.f,  -80.f,   51.f,  95.f},
    {-80.f,  -168.f,  95.f, 183.f},
    {-168.f, -344.f, 183.f, 359.f},
};

// ---------------- conv 3x3 SAME, optional ReLU, 8 output channels/block ----
__global__ __launch_bounds__(256) void conv3x3(
    const float* __restrict__ in, const float* __restrict__ w,
    const float* __restrict__ bias, float* __restrict__ out,
    int C, int H, int W, int relu, int nhwc)
{
    __shared__ float patch[10 * 34];
    const int tx = threadIdx.x, ty = threadIdx.y;
    const int tid = ty * 32 + tx;
    const int x0 = blockIdx.x * 32, y0 = blockIdx.y * 8;
    const int k0 = blockIdx.z * 8;
    const size_t HW = (size_t)H * W;

    float acc[8];
#pragma unroll
    for (int i = 0; i < 8; ++i) acc[i] = 0.f;

    for (int c = 0; c < C; ++c) {
        __syncthreads();
#pragma unroll
        for (int l = 0; l < 2; ++l) {
            int idx = tid + l * 256;
            if (idx < 340) {
                int py = idx / 34, px = idx - py * 34;
                int gy = y0 + py - 1, gx = x0 + px - 1;
                float v = 0.f;
                if (gy >= 0 && gy < H && gx >= 0 && gx < W)
                    v = nhwc ? in[((size_t)gy * W + gx) * C + c]
                             : in[(size_t)c * HW + (size_t)gy * W + gx];
                patch[idx] = v;
            }
        }
        __syncthreads();
        float r0 = patch[(ty + 0) * 34 + tx + 0];
        float r1 = patch[(ty + 0) * 34 + tx + 1];
        float r2 = patch[(ty + 0) * 34 + tx + 2];
        float r3 = patch[(ty + 1) * 34 + tx + 0];
        float r4 = patch[(ty + 1) * 34 + tx + 1];
        float r5 = patch[(ty + 1) * 34 + tx + 2];
        float r6 = patch[(ty + 2) * 34 + tx + 0];
        float r7 = patch[(ty + 2) * 34 + tx + 1];
        float r8 = patch[(ty + 2) * 34 + tx + 2];
        const float* wp = w + ((size_t)k0 * C + c) * 9;
#pragma unroll
        for (int ko = 0; ko < 8; ++ko) {
            const float* wk = wp + (size_t)ko * C * 9;
            acc[ko] += wk[0] * r0 + wk[1] * r1 + wk[2] * r2
                     + wk[3] * r3 + wk[4] * r4 + wk[5] * r5
                     + wk[6] * r6 + wk[7] * r7 + wk[8] * r8;
        }
    }

    int gx = x0 + tx, gy = y0 + ty;
    if (gx < W && gy < H) {
#pragma unroll
        for (int ko = 0; ko < 8; ++ko) {
            float v = acc[ko] + bias[k0 + ko];
            if (relu) v = fmaxf(v, 0.f);
            out[(size_t)(k0 + ko) * HW + (size_t)gy * W + gx] = v;
        }
    }
}

// ---------------- 2x2 stride-2 VALID maxpool --------------------------------
__global__ void maxpool2(const float* __restrict__ in, float* __restrict__ out,
                         int C, int H, int W)
{
    int Ho = H >> 1, Wo = W >> 1;
    int total = C * Ho * Wo;
    int idx = blockIdx.x * blockDim.x + threadIdx.x;
    if (idx >= total) return;
    int c = idx / (Ho * Wo);
    int r = idx - c * (Ho * Wo);
    int y = r / Wo, x = r - y * Wo;
    const float* p = in + (size_t)c * H * W + (size_t)(2 * y) * W + 2 * x;
    out[idx] = fmaxf(fmaxf(p[0], p[1]), fmaxf(p[W], p[W + 1]));
}

// ---------------- 1x1 conv (score / bbox heads) -----------------------------
__global__ void conv1x1(const float* __restrict__ in, const float* __restrict__ w,
                        const float* __restrict__ b, float* __restrict__ out,
                        int C, int P, int K)
{
    int p = blockIdx.x * blockDim.x + threadIdx.x;
    int k = blockIdx.y;
    if (p >= P || k >= K) return;
    const float* wr = w + (size_t)k * C;
    float acc = b[k];
    for (int c = 0; c < C; ++c) acc += wr[c] * in[(size_t)c * P + p];
    out[(size_t)k * P + p] = acc;
}

// ---------------- decode anchors + softmax score + sort keys ----------------
__global__ void decode_anchors(const float* __restrict__ score,
                               const float* __restrict__ bbox,
                               const float* __restrict__ iminfo,
                               float* __restrict__ boxes,
                               unsigned long long* __restrict__ keys)
{
    int idx = blockIdx.x * blockDim.x + threadIdx.x;
    if (idx >= NSORT) return;
    if (idx >= NANCH) { keys[idx] = ~0ULL; return; }
    int p = idx / 9, a = idx - p * 9;
    int y = p / FW, x = p - y * FW;

    float s0 = score[a * NPOS + p], s1 = score[(9 + a) * NPOS + p];
    float mx = fmaxf(s0, s1);
    float e0 = expf(s0 - mx), e1 = expf(s1 - mx);
    float prob = e1 / (e0 + e1);

    float ax1 = ANCHORS[a][0] + 16.f * x;
    float ay1 = ANCHORS[a][1] + 16.f * y;
    float ax2 = ANCHORS[a][2] + 16.f * x;
    float ay2 = ANCHORS[a][3] + 16.f * y;
    float aw = ax2 - ax1 + 1.f, ah = ay2 - ay1 + 1.f;
    float cx = ax1 + 0.5f * aw, cy = ay1 + 0.5f * ah;

    float d0 = bbox[(4 * a + 0) * NPOS + p];
    float d1 = bbox[(4 * a + 1) * NPOS + p];
    float d2 = bbox[(4 * a + 2) * NPOS + p];
    float d3 = bbox[(4 * a + 3) * NPOS + p];
    float pcx = d0 * aw + cx, pcy = d1 * ah + cy;
    float pw = expf(d2) * aw, ph = expf(d3) * ah;

    float imh = iminfo[0], imw = iminfo[1], sc = iminfo[2];
    float x1 = fminf(fmaxf(pcx - 0.5f * pw, 0.f), imw - 1.f);
    float y1 = fminf(fmaxf(pcy - 0.5f * ph, 0.f), imh - 1.f);
    float x2 = fminf(fmaxf(pcx + 0.5f * pw, 0.f), imw - 1.f);
    float y2 = fminf(fmaxf(pcy + 0.5f * ph, 0.f), imh - 1.f);
    boxes[idx * 4 + 0] = x1; boxes[idx * 4 + 1] = y1;
    boxes[idx * 4 + 2] = x2; boxes[idx * 4 + 3] = y2;

    float wsz = x2 - x1 + 1.f, hsz = y2 - y1 + 1.f;
    float ms = 16.f * sc;
    float s = (wsz >= ms && hsz >= ms) ? prob : -INFINITY;
    unsigned u = __float_as_uint(s);
    u = (u & 0x80000000u) ? ~u : (u | 0x80000000u);   // monotone flip
    unsigned k32 = ~u;                                 // descending order key
    keys[idx] = ((unsigned long long)k32 << 32) | (unsigned)idx;
}

// ---------------- bitonic sort step (ascending on packed key) ---------------
__global__ void bitonic_step(unsigned long long* __restrict__ keys, int j, int k)
{
    int i = blockIdx.x * blockDim.x + threadIdx.x;
    int ixj = i ^ j;
    if (ixj > i && ixj < NSORT) {
        unsigned long long a = keys[i], b = keys[ixj];
        bool up = ((i & k) == 0);
        if ((a > b) == up) { keys[i] = b; keys[ixj] = a; }
    }
}

// ---------------- gather top-6000 boxes ------------------------------------
__global__ void gather_top(const unsigned long long* __restrict__ keys,
                           const float* __restrict__ boxes, float* __restrict__ tb)
{
    int r = blockIdx.x * blockDim.x + threadIdx.x;
    if (r >= PRE_NMS) return;
    int idx = (int)(keys[r] & 0xffffffffULL);
    ((float4*)tb)[r] = ((const float4*)boxes)[idx];
}

// ---------------- per-row suppression bitmask -------------------------------
__global__ __launch_bounds__(128) void iou_sup(const float* __restrict__ tb,
                                               unsigned long long* __restrict__ sup)
{
    int i = blockIdx.x;
    int wj = threadIdx.x;
    if (wj >= NWORD) return;
    float4 bi = ((const float4*)tb)[i];
    float ai = (bi.z - bi.x + 1.f) * (bi.w - bi.y + 1.f);
    unsigned long long m = 0;
    int jbase = wj * 64;
    for (int b = 0; b < 64; ++b) {
        int j = jbase + b;
        if (j <= i || j >= PRE_NMS) continue;
        float4 bj = ((const float4*)tb)[j];
        float xx1 = fmaxf(bi.x, bj.x), yy1 = fmaxf(bi.y, bj.y);
        float xx2 = fminf(bi.z, bj.z), yy2 = fminf(bi.w, bj.w);
        float iw = fmaxf(xx2 - xx1 + 1.f, 0.f), ih = fmaxf(yy2 - yy1 + 1.f, 0.f);
        float inter = iw * ih;
        float aj = (bj.z - bj.x + 1.f) * (bj.w - bj.y + 1.f);
        float iou = inter / (ai + aj - inter);
        if (iou > 0.7f) m |= (1ULL << b);
    }
    sup[(size_t)i * NWORD + wj] = m;
}

// ---------------- sequential greedy NMS scan --------------------------------
__global__ __launch_bounds__(128) void nms_seq(const unsigned long long* __restrict__ sup,
                                               unsigned long long* __restrict__ keepg)
{
    __shared__ unsigned long long keep[NWORD];
    int t = threadIdx.x;
    if (t < NWORD) keep[t] = ~0ULL;
    __syncthreads();
    for (int i = 0; i < PRE_NMS; ++i) {
        bool k = (keep[i >> 6] >> (i & 63)) & 1ULL;
        __syncthreads();
        if (k && t < NWORD) keep[t] &= ~sup[(size_t)i * NWORD + t];
        __syncthreads();
    }
    if (t < NWORD) keepg[t] = keep[t];
}

// ---------------- select 300 rois (kept first, then unkept, stable) ---------
__global__ void select_rois(const unsigned long long* __restrict__ keepg,
                            const float* __restrict__ tb,
                            float* __restrict__ rois, float* __restrict__ out_rois)
{
    if (threadIdx.x != 0 || blockIdx.x != 0) return;
    int cnt = 0;
    for (int pass = 0; pass < 2 && cnt < POST_NMS; ++pass) {
        for (int i = 0; i < PRE_NMS && cnt < POST_NMS; ++i) {
            bool k = (keepg[i >> 6] >> (i & 63)) & 1ULL;
            if ((pass == 0) == k) {
                float v0 = 0.f;
                float v1 = tb[i * 4 + 0], v2 = tb[i * 4 + 1];
                float v3 = tb[i * 4 + 2], v4 = tb[i * 4 + 3];
                rois[cnt * 5 + 0] = v0; rois[cnt * 5 + 1] = v1; rois[cnt * 5 + 2] = v2;
                rois[cnt * 5 + 3] = v3; rois[cnt * 5 + 4] = v4;
                out_rois[cnt * 5 + 0] = v0; out_rois[cnt * 5 + 1] = v1; out_rois[cnt * 5 + 2] = v2;
                out_rois[cnt * 5 + 3] = v3; out_rois[cnt * 5 + 4] = v4;
                ++cnt;
            }
        }
    }
}

// ---------------- ROI max-pool 7x7 ------------------------------------------
__global__ __launch_bounds__(256) void roi_pool(const float* __restrict__ feat,
                                                const float* __restrict__ rois,
                                                float* __restrict__ pooled)
{
    int b = blockIdx.x;
    const float* r = rois + b * 5;
    int x1 = (int)rintf(r[1] * 0.0625f);
    int y1 = (int)rintf(r[2] * 0.0625f);
    int x2 = (int)rintf(r[3] * 0.0625f);
    int y2 = (int)rintf(r[4] * 0.0625f);
    float bh = (float)max(y2 - y1 + 1, 1) / 7.f;
    float bw = (float)max(x2 - x1 + 1, 1) / 7.f;
    for (int o = threadIdx.x; o < 512 * 49; o += 256) {
        int c = o / 49, rem = o - c * 49;
        int ph = rem / 7, pw = rem - ph * 7;
        int hs = min(max((int)floorf(ph * bh) + y1, 0), FH);
        int he = min(max((int)ceilf((ph + 1) * bh) + y1, 0), FH);
        int wst = min(max((int)floorf(pw * bw) + x1, 0), FW);
        int wen = min(max((int)ceilf((pw + 1) * bw) + x1, 0), FW);
        float m = -INFINITY;
        for (int yy = hs; yy < he; ++yy)
            for (int xx = wst; xx < wen; ++xx)
                m = fmaxf(m, feat[c * NPOS + yy * FW + xx]);
        pooled[(size_t)b * 25088 + o] = (he > hs && wen > wst) ? m : 0.f;
    }
}

// ---------------- GEMM: out[M,N] = A[M,K] * W[N,K]^T + b, opt ReLU ----------
// block tile M=16, N=256, K-chunk 32; thread tile 4x4.
__global__ __launch_bounds__(256) void gemm_nt(const float* __restrict__ A,
                                               const float* __restrict__ Wt,
                                               const float* __restrict__ bias,
                                               float* __restrict__ out,
                                               int M, int N, int K, int relu)
{
    __shared__ float Ws[32 * 260];
    __shared__ float As[32 * 20];
    int t = threadIdx.x;
    int n0 = blockIdx.x * 256, m0 = blockIdx.y * 16;
    int tnn = t & 63, tmm = t >> 6;
    float acc[4][4];
#pragma unroll
    for (int i = 0; i < 4; ++i)
#pragma unroll
        for (int j = 0; j < 4; ++j) acc[i][j] = 0.f;

    for (int k0 = 0; k0 < K; k0 += 32) {
        __syncthreads();
        {
            const float4* wr = (const float4*)(Wt + (size_t)(n0 + t) * K + k0);
#pragma unroll
            for (int q = 0; q < 8; ++q) {
                float4 v = wr[q];
                Ws[(4 * q + 0) * 260 + t] = v.x;
                Ws[(4 * q + 1) * 260 + t] = v.y;
                Ws[(4 * q + 2) * 260 + t] = v.z;
                Ws[(4 * q + 3) * 260 + t] = v.w;
            }
        }
        if (t < 128) {
            int m = t >> 3, q = t & 7;
            float4 v = make_float4(0.f, 0.f, 0.f, 0.f);
            if (m0 + m < M) v = *(const float4*)(A + (size_t)(m0 + m) * K + k0 + 4 * q);
            As[(4 * q + 0) * 20 + m] = v.x;
            As[(4 * q + 1) * 20 + m] = v.y;
            As[(4 * q + 2) * 20 + m] = v.z;
            As[(4 * q + 3) * 20 + m] = v.w;
        }
        __syncthreads();
#pragma unroll 8
        for (int kk = 0; kk < 32; ++kk) {
            float4 wv = *(const float4*)&Ws[kk * 260 + tnn * 4];
            float4 av = *(const float4*)&As[kk * 20 + tmm * 4];
            acc[0][0] += av.x * wv.x; acc[0][1] += av.x * wv.y;
            acc[0][2] += av.x * wv.z; acc[0][3] += av.x * wv.w;
            acc[1][0] += av.y * wv.x; acc[1][1] += av.y * wv.y;
            acc[1][2] += av.y * wv.z; acc[1][3] += av.y * wv.w;
            acc[2][0] += av.z * wv.x; acc[2][1] += av.z * wv.y;
            acc[2][2] += av.z * wv.z; acc[2][3] += av.z * wv.w;
            acc[3][0] += av.w * wv.x; acc[3][1] += av.w * wv.y;
            acc[3][2] += av.w * wv.z; acc[3][3] += av.w * wv.w;
        }
    }
    int n = n0 + tnn * 4;
    float4 bv = *(const float4*)(bias + n);
#pragma unroll
    for (int i = 0; i < 4; ++i) {
        int m = m0 + tmm * 4 + i;
        if (m < M) {
            float4 o;
            o.x = acc[i][0] + bv.x; o.y = acc[i][1] + bv.y;
            o.z = acc[i][2] + bv.z; o.w = acc[i][3] + bv.w;
            if (relu) {
                o.x = fmaxf(o.x, 0.f); o.y = fmaxf(o.y, 0.f);
                o.z = fmaxf(o.z, 0.f); o.w = fmaxf(o.w, 0.f);
            }
            *(float4*)(out + (size_t)m * N + n) = o;
        }
    }
}

// ---------------- small-N FC (cls=21, breg=84) ------------------------------
__global__ void fc_small(const float* __restrict__ A, const float* __restrict__ Wt,
                         const float* __restrict__ bias, float* __restrict__ out,
                         int N, int K)
{
    int m = blockIdx.x, n = threadIdx.x;
    if (n >= N) return;
    const float4* a = (const float4*)(A + (size_t)m * K);
    const float4* w = (const float4*)(Wt + (size_t)n * K);
    float acc = bias[n];
    for (int q = 0; q < K / 4; ++q) {
        float4 av = a[q], wv = w[q];
        acc += av.x * wv.x + av.y * wv.y + av.z * wv.z + av.w * wv.w;
    }
    out[(size_t)m * N + n] = acc;
}

// ---------------- row softmax over 21 classes -------------------------------
__global__ void softmax21(const float* __restrict__ in, float* __restrict__ out)
{
    int r = blockIdx.x * blockDim.x + threadIdx.x;
    if (r >= POST_NMS) return;
    const float* x = in + r * 21;
    float m = x[0];
    for (int j = 1; j < 21; ++j) m = fmaxf(m, x[j]);
    float e[21], s = 0.f;
    for (int j = 0; j < 21; ++j) { e[j] = expf(x[j] - m); s += e[j]; }
    float inv = 1.f / s;
    for (int j = 0; j < 21; ++j) out[r * 21 + j] = e[j] * inv;
}

// ===========================================================================
extern "C" void kernel_launch(void* const* d_in, const int* in_sizes, int n_in,
                              void* d_out, int out_size, void* d_ws, size_t ws_size,
                              hipStream_t stream)
{
    const float* im_data = (const float*)d_in[0];
    const float* im_info = (const float*)d_in[1];
    const float* vw[13]; const float* vb[13];
    for (int i = 0; i < 13; ++i) { vw[i] = (const float*)d_in[2 + 2 * i]; vb[i] = (const float*)d_in[3 + 2 * i]; }
    const float* rpn_w   = (const float*)d_in[28];
    const float* rpn_b   = (const float*)d_in[29];
    const float* score_w = (const float*)d_in[30];
    const float* score_b = (const float*)d_in[31];
    const float* bbox_w  = (const float*)d_in[32];
    const float* bbox_b  = (const float*)d_in[33];
    const float* fc6_w   = (const float*)d_in[34];
    const float* fc6_b   = (const float*)d_in[35];
    const float* fc7_w   = (const float*)d_in[36];
    const float* fc7_b   = (const float*)d_in[37];
    const float* cls_w   = (const float*)d_in[38];
    const float* cls_b   = (const float*)d_in[39];
    const float* breg_w  = (const float*)d_in[40];
    const float* breg_b  = (const float*)d_in[41];

    float* ws = (float*)d_ws;
    // workspace offsets (floats)
    const size_t oA    = 0;                       // 38,400,000 (64*600*1000)
    const size_t oB    = 38400000;                // ping-pong buffer
    const size_t oF    = 76800000;                // feat 512*2294
    const size_t oRPN  = oF    + 1174528;
    const size_t oSC   = oRPN  + 1174528;         // 18*2294
    const size_t oBB   = oSC   + 41292;           // 36*2294
    const size_t oBOX  = oBB   + 82584;           // 20646*4
    const size_t oKEY  = oBOX  + 82584;           // 32768 u64 (as 65536 floats)
    const size_t oTB   = oKEY  + 65536;           // 6000*4
    const size_t oSUP  = oTB   + 24000;           // 6000*94 u64
    const size_t oKEEP = oSUP  + 1128000;         // 94 u64 (padded)
    const size_t oROI  = oKEEP + 256;             // 300*5 (padded)
    const size_t oPOOL = oROI  + 1536;            // 300*25088
    const size_t oH6   = oPOOL + 7526400;         // 300*4096
    const size_t oH7   = oH6   + 1228800;
    const size_t oCLS  = oH7   + 1228800;         // 300*21 (padded)
    // total ≈ 90,565,244 floats ≈ 363 MB — must fit in ws_size

    float* bufA = ws + oA;
    float* bufB = ws + oB;
    float* feat = ws + oF;
    float* rpn  = ws + oRPN;
    float* scr  = ws + oSC;
    float* bbx  = ws + oBB;
    float* boxes = ws + oBOX;
    unsigned long long* keys = (unsigned long long*)(ws + oKEY);
    float* tb = ws + oTB;
    unsigned long long* sup = (unsigned long long*)(ws + oSUP);
    unsigned long long* keepg = (unsigned long long*)(ws + oKEEP);
    float* rois = ws + oROI;
    float* pooled = ws + oPOOL;
    float* h6 = ws + oH6;
    float* h7 = ws + oH7;
    float* clsb = ws + oCLS;

    float* out = (float*)d_out;          // cls_prob[6300] | bbox_pred[25200] | rois[1500]
    float* out_bbox = out + 6300;
    float* out_rois = out + 31500;

    dim3 cblk(32, 8);
    auto conv = [&](const float* in, const float* w, const float* b, float* o,
                    int C, int H, int W, int K, int relu, int nhwc) {
        dim3 grid((W + 31) / 32, (H + 7) / 8, K / 8);
        conv3x3<<<grid, cblk, 0, stream>>>(in, w, b, o, C, H, W, relu, nhwc);
    };
    auto pool = [&](const float* in, float* o, int C, int H, int W) {
        int total = C * (H / 2) * (W / 2);
        maxpool2<<<(total + 255) / 256, 256, 0, stream>>>(in, o, C, H, W);
    };

    // ---- VGG16 backbone ----
    conv(im_data, vw[0], vb[0], bufA, 3, 600, 1000, 64, 1, 1);
    conv(bufA, vw[1], vb[1], bufB, 64, 600, 1000, 64, 1, 0);
    pool(bufB, bufA, 64, 600, 1000);                       // 300x500
    conv(bufA, vw[2], vb[2], bufB, 64, 300, 500, 128, 1, 0);
    conv(bufB, vw[3], vb[3], bufA, 128, 300, 500, 128, 1, 0);
    pool(bufA, bufB, 128, 300, 500);                       // 150x250
    conv(bufB, vw[4], vb[4], bufA, 128, 150, 250, 256, 1, 0);
    conv(bufA, vw[5], vb[5], bufB, 256, 150, 250, 256, 1, 0);
    conv(bufB, vw[6], vb[6], bufA, 256, 150, 250, 256, 1, 0);
    pool(bufA, bufB, 256, 150, 250);                       // 75x125
    conv(bufB, vw[7], vb[7], bufA, 256, 75, 125, 512, 1, 0);
    conv(bufA, vw[8], vb[8], bufB, 512, 75, 125, 512, 1, 0);
    conv(bufB, vw[9], vb[9], bufA, 512, 75, 125, 512, 1, 0);
    pool(bufA, bufB, 512, 75, 125);                        // 37x62
    conv(bufB, vw[10], vb[10], bufA, 512, FH, FW, 512, 1, 0);
    conv(bufA, vw[11], vb[11], bufB, 512, FH, FW, 512, 1, 0);
    conv(bufB, vw[12], vb[12], feat, 512, FH, FW, 512, 1, 0);

    // ---- RPN ----
    conv(feat, rpn_w, rpn_b, rpn, 512, FH, FW, 512, 1, 0);
    {
        dim3 g((NPOS + 255) / 256, 18);
        conv1x1<<<g, 256, 0, stream>>>(rpn, score_w, score_b, scr, 512, NPOS, 18);
    }
    {
        dim3 g((NPOS + 255) / 256, 36);
        conv1x1<<<g, 256, 0, stream>>>(rpn, bbox_w, bbox_b, bbx, 512, NPOS, 36);
    }

    // ---- proposals ----
    decode_anchors<<<NSORT / 256, 256, 0, stream>>>(scr, bbx, im_info, boxes, keys);
    for (int k = 2; k <= NSORT; k <<= 1)
        for (int j = k >> 1; j > 0; j >>= 1)
            bitonic_step<<<NSORT / 256, 256, 0, stream>>>(keys, j, k);
    gather_top<<<(PRE_NMS + 255) / 256, 256, 0, stream>>>(keys, boxes, tb);
    iou_sup<<<PRE_NMS, 128, 0, stream>>>(tb, sup);
    nms_seq<<<1, 128, 0, stream>>>(sup, keepg);
    select_rois<<<1, 64, 0, stream>>>(keepg, tb, rois, out_rois);

    // ---- ROI pool + FC head ----
    roi_pool<<<POST_NMS, 256, 0, stream>>>(feat, rois, pooled);
    {
        dim3 g(4096 / 256, (POST_NMS + 15) / 16);
        gemm_nt<<<g, 256, 0, stream>>>(pooled, fc6_w, fc6_b, h6, POST_NMS, 4096, 25088, 1);
        gemm_nt<<<g, 256, 0, stream>>>(h6, fc7_w, fc7_b, h7, POST_NMS, 4096, 4096, 1);
    }
    fc_small<<<POST_NMS, 96, 0, stream>>>(h7, cls_w, cls_b, clsb, 21, 4096);
    fc_small<<<POST_NMS, 96, 0, stream>>>(h7, breg_w, breg_b, out_bbox, 84, 4096);
    softmax21<<<(POST_NMS + 255) / 256, 256, 0, stream>>>(clsb, out);
    (void)in_sizes; (void)n_in; (void)out_size; (void)ws_size;
}